// Round 6
// baseline (75987.909 us; speedup 1.0000x reference)
//
#include <hip/hip_runtime.h>
#include <cstdint>
#include <cstddef>

#define NWG 128
#define NTHR 512
#define UPW 8  // hidden units per WG
#define TSTEPS 16384
#define HDIM 1024
#define EDIM 13
#define HLDIM 512

typedef unsigned long long ull;

// ---------------------------------------------------------------------------
// Init kernel: re-arm the tagged h-record ring and u-record every call (d_ws
// is poisoned once with 0xAA and never re-poisoned between graph replays; a
// finished replay also leaves end-state tags behind, so every tag word must
// be rewritten each launch).
// hrec[parity][i] = { low32: f32 h value, high32: u32 step tag }, 4 parities.
// ---------------------------------------------------------------------------
__global__ void k_init(const float* __restrict__ h0, ull* __restrict__ hrec,
                       ull* __restrict__ urec) {
  int i = threadIdx.x;  // 1024 threads
  hrec[i] = (ull)__float_as_uint(h0[i]);  // {h0, tag=0}
  hrec[HDIM + i] = 0ull;
  hrec[2 * HDIM + i] = 0ull;
  hrec[3 * HDIM + i] = 0ull;
  if (i < HLDIM) urec[i] = 0ull;
}

// ---------------------------------------------------------------------------
// Persistent LSTM kernel, LDS-resident weights (compiler-proof residency).
// 128 WGs x 512 threads. WG w owns units [8w, 8w+8) -> 32 gate rows; the
// 128 KB W_hh chunk lives in static LDS (total ~142 KB -> exactly 1 WG/CU,
// no register-allocator involvement: rounds 3-5 proved VGPR pinning fails
// (VGPR_Count 88/92/60 - W spilled to scratch; FETCH_SIZE +0.7GB = ~43KB/step
// of reload misses; ~1.9us/step through L2 was the dominant cost).
// Wave v owns unit 8w+v: its 4 gate rows reduce fully in-wave; lane 0 owns
// the cell state, computes activations, publishes. One barrier per step.
// Cross-WG sync: self-validating {value, tag} records, 4-deep parity ring,
// relaxed agent-scope 64-bit atomics (single-copy, serviced at the device
// coherent point -> immune to non-coherent per-XCD L2s). s_sleep backoff.
// ---------------------------------------------------------------------------
__global__ __launch_bounds__(NTHR) void k_main(
    const float* __restrict__ x, const float* __restrict__ c0,
    const float* __restrict__ Wih, const float* __restrict__ Whh,
    const float* __restrict__ bih, const float* __restrict__ bhh,
    const float* __restrict__ W1, const float* __restrict__ b1,
    const float* __restrict__ W2, const float* __restrict__ b2,
    float* __restrict__ out, ull* hrec, ull* urec) {
  const int w = blockIdx.x;
  const int tid = threadIdx.x;
  const int wave = tid >> 6;  // 0..7 == local unit
  const int lane = tid & 63;

  // ---- LDS: 32x256 float4 W (128 KB) + double-buffered h + misc ----------
  __shared__ float4 lds_w4[32 * 256];     // [local_row][col4], row = 4*v+g
  __shared__ float4 lds_h4[2 * 256];      // [parity][col4]
  __shared__ float lds_x[2][16];
  __shared__ float lds_wih[32][17];       // stride 17: conflict-free
  __shared__ float lds_bsum[32];
  __shared__ float lds_r0[8], lds_r1[8];

  // ---- stage W_hh chunk into LDS (one-time, coalesced) -------------------
#pragma unroll
  for (int it = 0; it < 16; ++it) {
    int idx = it * NTHR + tid;  // 0..8191 float4s
    int r = idx >> 8;           // local row 0..31  (r = 4*v + g)
    int c4 = idx & 255;
    int v0_ = r >> 2, g0_ = r & 3;
    int grow = g0_ * HDIM + UPW * w + v0_;
    lds_w4[r * 256 + c4] =
        ((const float4*)(Whh + (size_t)grow * HDIM))[c4];
  }
  if (tid < 32) {
    int v0_ = tid >> 2, g0_ = tid & 3;
    int grow = g0_ * HDIM + UPW * w + v0_;
#pragma unroll
    for (int e = 0; e < EDIM; ++e) lds_wih[tid][e] = Wih[grow * EDIM + e];
    lds_bsum[tid] = bih[grow] + bhh[grow];
  }
  // cell state: lane 0 of wave v owns unit 8w+v
  float cst = c0[UPW * w + wave];
  __syncthreads();

  const int myg = lane & 3;                     // gate this lane activates
  const float gsc = (myg == 2) ? 2.f : 1.f;     // tanh via 2*sigmoid(2x)-1
  const float4* wb = lds_w4 + (wave * 4) * 256; // this wave's 4 rows

  for (int t = 1; t <= TSTEPS; ++t) {
    const int lp = (t - 1) & 1;
    // ---- x_t prefetch: issue before the poll so latency hides there
    float xv = 0.f;
    if (tid < EDIM) xv = x[(size_t)(t - 1) * EDIM + tid];

    // ---- poll 2 adjacent {h, tag} records of h_{t-1}; the poll load IS the
    // data load (one coherent round trip). s_sleep backoff cuts probe rate.
    const ull* src = hrec + (size_t)((t - 1) & 3) * HDIM;
    const unsigned want = (unsigned)(t - 1);
    ull r0 = __hip_atomic_load(&src[2 * tid], __ATOMIC_RELAXED,
                               __HIP_MEMORY_SCOPE_AGENT);
    ull r1 = __hip_atomic_load(&src[2 * tid + 1], __ATOMIC_RELAXED,
                               __HIP_MEMORY_SCOPE_AGENT);
    for (;;) {
      bool b0 = (unsigned)(r0 >> 32) == want;
      bool b1 = (unsigned)(r1 >> 32) == want;
      if (b0 && b1) break;
      __builtin_amdgcn_s_sleep(2);
      if (!b0)
        r0 = __hip_atomic_load(&src[2 * tid], __ATOMIC_RELAXED,
                               __HIP_MEMORY_SCOPE_AGENT);
      if (!b1)
        r1 = __hip_atomic_load(&src[2 * tid + 1], __ATOMIC_RELAXED,
                               __HIP_MEMORY_SCOPE_AGENT);
    }
    float2 hv;
    hv.x = __uint_as_float((unsigned)r0);
    hv.y = __uint_as_float((unsigned)r1);
    ((float2*)lds_h4)[lp * 512 + tid] = hv;
    if (tid < EDIM) lds_x[lp][tid] = xv;
    __syncthreads();

    // ---- h fragment into registers (4 float4s, reused across 4 rows)
    const float4* hb = lds_h4 + lp * 256;
    float4 h0 = hb[lane], h1 = hb[lane + 64], h2 = hb[lane + 128],
           h3 = hb[lane + 192];

    // ---- 4 gate rows of this wave's unit: 16 W reads, 64 FMA
    float acc0, acc1, acc2, acc3;
    {
      float4 a = wb[lane], b = wb[lane + 64], c = wb[lane + 128],
             d = wb[lane + 192];
      acc0 = (a.x * h0.x + a.y * h0.y + a.z * h0.z + a.w * h0.w) +
             (b.x * h1.x + b.y * h1.y + b.z * h1.z + b.w * h1.w) +
             (c.x * h2.x + c.y * h2.y + c.z * h2.z + c.w * h2.w) +
             (d.x * h3.x + d.y * h3.y + d.z * h3.z + d.w * h3.w);
    }
    {
      const float4* wr = wb + 256;
      float4 a = wr[lane], b = wr[lane + 64], c = wr[lane + 128],
             d = wr[lane + 192];
      acc1 = (a.x * h0.x + a.y * h0.y + a.z * h0.z + a.w * h0.w) +
             (b.x * h1.x + b.y * h1.y + b.z * h1.z + b.w * h1.w) +
             (c.x * h2.x + c.y * h2.y + c.z * h2.z + c.w * h2.w) +
             (d.x * h3.x + d.y * h3.y + d.z * h3.z + d.w * h3.w);
    }
    {
      const float4* wr = wb + 512;
      float4 a = wr[lane], b = wr[lane + 64], c = wr[lane + 128],
             d = wr[lane + 192];
      acc2 = (a.x * h0.x + a.y * h0.y + a.z * h0.z + a.w * h0.w) +
             (b.x * h1.x + b.y * h1.y + b.z * h1.z + b.w * h1.w) +
             (c.x * h2.x + c.y * h2.y + c.z * h2.z + c.w * h2.w) +
             (d.x * h3.x + d.y * h3.y + d.z * h3.z + d.w * h3.w);
    }
    {
      const float4* wr = wb + 768;
      float4 a = wr[lane], b = wr[lane + 64], c = wr[lane + 128],
             d = wr[lane + 192];
      acc3 = (a.x * h0.x + a.y * h0.y + a.z * h0.z + a.w * h0.w) +
             (b.x * h1.x + b.y * h1.y + b.z * h1.z + b.w * h1.w) +
             (c.x * h2.x + c.y * h2.y + c.z * h2.z + c.w * h2.w) +
             (d.x * h3.x + d.y * h3.y + d.z * h3.z + d.w * h3.w);
    }

    // ---- fold x-projection + biases in (lane g handles gate g, pre-reduce)
    if (lane < 4) {
      int lrow = wave * 4 + lane;
      float xd = lds_bsum[lrow];
#pragma unroll
      for (int e = 0; e < EDIM; ++e) xd += lds_wih[lrow][e] * lds_x[lp][e];
      if (lane == 0) acc0 += xd;
      else if (lane == 1) acc1 += xd;
      else if (lane == 2) acc2 += xd;
      else acc3 += xd;
    }

    // ---- in-wave reduce: all lanes end with all 4 gate sums
#pragma unroll
    for (int m = 1; m < 64; m <<= 1) {
      acc0 += __shfl_xor(acc0, m);
      acc1 += __shfl_xor(acc1, m);
      acc2 += __shfl_xor(acc2, m);
      acc3 += __shfl_xor(acc3, m);
    }

    // ---- activations: lane j computes gate j (parallel exp chains)
    float pre = (myg == 0) ? acc0 : (myg == 1) ? acc1 : (myg == 2) ? acc2
                                                                   : acc3;
    float e = __expf(-gsc * pre);
    float y = 1.f / (1.f + e);
    float act = (myg == 2) ? 2.f * y - 1.f : y;

    float ai = __shfl(act, 0);
    float af = __shfl(act, 1);
    float ag = __shfl(act, 2);
    float ao = __shfl(act, 3);
    if (lane == 0) {
      cst = af * cst + ai * ag;
      float e2 = __expf(-2.f * cst);
      float hn = ao * (2.f / (1.f + e2) - 1.f);
      ull pk = ((ull)(unsigned)t << 32) | (ull)__float_as_uint(hn);
      __hip_atomic_store(&hrec[(size_t)(t & 3) * HDIM + UPW * w + wave], pk,
                         __ATOMIC_RELAXED, __HIP_MEMORY_SCOPE_AGENT);
    }
    // no end-of-step barrier: publish is self-validating; LDS h parity is
    // reused 2 steps later, ordered by the intervening step's barrier.
  }

  // ---- tail step 1: u = tanh(W1 @ h_T + b1), 4 rows per WG ---------------
  {
    const unsigned want = (unsigned)TSTEPS;  // parity (TSTEPS & 3) == 0
    ull r0 = __hip_atomic_load(&hrec[2 * tid], __ATOMIC_RELAXED,
                               __HIP_MEMORY_SCOPE_AGENT);
    ull r1 = __hip_atomic_load(&hrec[2 * tid + 1], __ATOMIC_RELAXED,
                               __HIP_MEMORY_SCOPE_AGENT);
    for (;;) {
      bool b0 = (unsigned)(r0 >> 32) == want;
      bool b1 = (unsigned)(r1 >> 32) == want;
      if (b0 && b1) break;
      __builtin_amdgcn_s_sleep(2);
      if (!b0)
        r0 = __hip_atomic_load(&hrec[2 * tid], __ATOMIC_RELAXED,
                               __HIP_MEMORY_SCOPE_AGENT);
      if (!b1)
        r1 = __hip_atomic_load(&hrec[2 * tid + 1], __ATOMIC_RELAXED,
                               __HIP_MEMORY_SCOPE_AGENT);
    }
    float2 hv;
    hv.x = __uint_as_float((unsigned)r0);
    hv.y = __uint_as_float((unsigned)r1);
    ((float2*)lds_h4)[tid] = hv;  // parity-0 slot
  }
  __syncthreads();
  if (wave < 4) {
    int r1i = 4 * w + wave;  // one MLP row per wave, 512 rows over 128 WGs
    const float* hf = (const float*)lds_h4;
    const float* w1p = W1 + (size_t)r1i * HDIM + lane * 16;
    float a0 = 0.f, a1 = 0.f;
#pragma unroll
    for (int i = 0; i < 16; i += 2) {
      a0 += w1p[i] * hf[lane * 16 + i];
      a1 += w1p[i + 1] * hf[lane * 16 + i + 1];
    }
    float acc1 = a0 + a1;
#pragma unroll
    for (int m = 1; m < 64; m <<= 1) acc1 += __shfl_xor(acc1, m);
    if (lane == 0) {
      float e2 = __expf(-2.f * (acc1 + b1[r1i]));
      float u = 2.f / (1.f + e2) - 1.f;
      ull pk = (1ull << 32) | (ull)__float_as_uint(u);
      __hip_atomic_store(&urec[r1i], pk, __ATOMIC_RELAXED,
                         __HIP_MEMORY_SCOPE_AGENT);
    }
  }

  // ---- tail step 2: out = W2 @ u + b2, WG 0 only -------------------------
  if (w == 0) {
    ull uv = __hip_atomic_load(&urec[tid], __ATOMIC_RELAXED,
                               __HIP_MEMORY_SCOPE_AGENT);
    while ((unsigned)(uv >> 32) != 1u) {
      __builtin_amdgcn_s_sleep(2);
      uv = __hip_atomic_load(&urec[tid], __ATOMIC_RELAXED,
                             __HIP_MEMORY_SCOPE_AGENT);
    }
    float u = __uint_as_float((unsigned)uv);
    float p0 = W2[tid] * u;
    float p1 = W2[HLDIM + tid] * u;
#pragma unroll
    for (int m = 1; m < 64; m <<= 1) {
      p0 += __shfl_xor(p0, m);
      p1 += __shfl_xor(p1, m);
    }
    if (lane == 0) {
      lds_r0[wave] = p0;
      lds_r1[wave] = p1;
    }
    __syncthreads();
    if (tid == 0) {
      float o0 = b2[0], o1 = b2[1];
#pragma unroll
      for (int k = 0; k < 8; ++k) {
        o0 += lds_r0[k];
        o1 += lds_r1[k];
      }
      out[0] = o0;
      out[1] = o1;
    }
  }
}

extern "C" void kernel_launch(void* const* d_in, const int* in_sizes, int n_in,
                              void* d_out, int out_size, void* d_ws,
                              size_t ws_size, hipStream_t stream) {
  const float* x = (const float*)d_in[0];
  const float* h0 = (const float*)d_in[1];
  const float* c0 = (const float*)d_in[2];
  const float* Wih = (const float*)d_in[3];
  const float* Whh = (const float*)d_in[4];
  const float* bih = (const float*)d_in[5];
  const float* bhh = (const float*)d_in[6];
  const float* W1 = (const float*)d_in[7];
  const float* b1 = (const float*)d_in[8];
  const float* W2 = (const float*)d_in[9];
  const float* b2 = (const float*)d_in[10];
  float* out = (float*)d_out;

  ull* hrec = (ull*)d_ws;                                    // 4*1024*8 = 32 KB
  ull* urec = (ull*)((char*)d_ws + 4 * HDIM * sizeof(ull));  // 4 KB

  k_init<<<1, 1024, 0, stream>>>(h0, hrec, urec);
  k_main<<<NWG, NTHR, 0, stream>>>(x, c0, Wih, Whh, bih, bhh, W1, b1, W2, b2,
                                   out, hrec, urec);
}